// Round 1
// baseline (432.864 us; speedup 1.0000x reference)
//
#include <hip/hip_runtime.h>
#include <hip/hip_bf16.h>

#define B_DIM 64
#define M_DIM 8192
#define V_DIM 128
#define EPS 1e-8f
#define KCAP 2048

// ---------------- Kernel 1: cosine similarity ----------------
// grid (M/32, B), block 256. Each 32-lane group handles one row per rt-iter
// (4 iters -> 32 rows/block). float4 loads: 16B/lane, fully coalesced.
__global__ void sim_kernel(const float* __restrict__ mem,
                           const float* __restrict__ v,
                           float* __restrict__ sim) {
    const int b   = blockIdx.y;
    const int m0  = blockIdx.x * 32;
    const int tid = threadIdx.x;

    __shared__ float vs[V_DIM];
    __shared__ float s_bn;

    if (tid < V_DIM) vs[tid] = v[b * V_DIM + tid] + EPS;
    __syncthreads();

    if (tid < 32) {
        float s = 0.f;
#pragma unroll
        for (int j = 0; j < 4; ++j) { float x = vs[tid + 32 * j]; s += x * x; }
#pragma unroll
        for (int mk = 16; mk; mk >>= 1) s += __shfl_xor(s, mk, 32);
        if (tid == 0) s_bn = sqrtf(s);
    }
    __syncthreads();

    const int r    = tid >> 5;   // 0..7
    const int lane = tid & 31;
    const int c    = lane * 4;
    const float bn = s_bn;

#pragma unroll
    for (int rt = 0; rt < 4; ++rt) {
        const int m = m0 + rt * 8 + r;
        const float4* rowp =
            reinterpret_cast<const float4*>(mem + ((size_t)b * M_DIM + m) * V_DIM);
        float4 x = rowp[lane];
        float a0 = x.x + EPS, a1 = x.y + EPS, a2 = x.z + EPS, a3 = x.w + EPS;
        float dot = a0 * vs[c] + a1 * vs[c + 1] + a2 * vs[c + 2] + a3 * vs[c + 3];
        float ss  = a0 * a0 + a1 * a1 + a2 * a2 + a3 * a3;
#pragma unroll
        for (int mk = 16; mk; mk >>= 1) {
            dot += __shfl_xor(dot, mk, 32);
            ss  += __shfl_xor(ss,  mk, 32);
        }
        if (lane == 0) {
            float denom = fmaxf(sqrtf(ss) * bn, EPS);
            sim[(size_t)b * M_DIM + m] = dot / denom;
        }
    }
}

// ---------------- Kernel 2: exact top-k + fused write/read ----------------
// One block per batch. Radix-select the exact kth-largest sim (bit-exact tie
// semantics vs reference's  w = where(sim >= kth, sim, 0) ), then
// read[b,:] = sum_kept w*mem_row + (sum w^2) * v[b,:].
__device__ __forceinline__ unsigned int f2key(float f) {
    unsigned int u = __float_as_uint(f);
    return (u & 0x80000000u) ? ~u : (u | 0x80000000u);
}
__device__ __forceinline__ float key2f(unsigned int k) {
    return (k & 0x80000000u) ? __uint_as_float(k & 0x7FFFFFFFu)
                             : __uint_as_float(~k);
}

__global__ void topk_read_kernel(const float* __restrict__ mem,
                                 const float* __restrict__ v,
                                 const float* __restrict__ sim,
                                 const int* __restrict__ topk_p,
                                 float* __restrict__ out) {
    const int b   = blockIdx.x;
    const int tid = threadIdx.x;
    const int NT  = 256;

    __shared__ unsigned int keys[M_DIM];      // 32 KB
    __shared__ unsigned int hist[256];        // 1 KB
    __shared__ unsigned int s_prefix;
    __shared__ int s_k;
    __shared__ int s_cnt;
    __shared__ int   s_idx[KCAP];             // 8 KB
    __shared__ float s_w[KCAP];               // 8 KB
    __shared__ float s_sumw2;
    __shared__ float s_acc[256];              // 1 KB

    for (int i = tid; i < M_DIM; i += NT)
        keys[i] = f2key(sim[(size_t)b * M_DIM + i]);
    if (tid == 0) { s_prefix = 0u; s_k = topk_p[0]; s_cnt = 0; }
    __syncthreads();

    // 4-round byte radix select for kth largest
    for (int p = 3; p >= 0; --p) {
        hist[tid & 255] = 0u;   // NT==256 -> each bucket zeroed exactly once
        __syncthreads();
        const unsigned int dm = (p == 3) ? 0u : (0xFFFFFFFFu << ((p + 1) * 8));
        const unsigned int pf = s_prefix;
        for (int i = tid; i < M_DIM; i += NT) {
            unsigned int ky = keys[i];
            if ((ky & dm) == pf)
                atomicAdd(&hist[(ky >> (p * 8)) & 0xFFu], 1u);
        }
        __syncthreads();
        if (tid == 0) {
            int k = s_k;
            for (int vq = 255; vq >= 0; --vq) {
                int c = (int)hist[vq];
                if (k <= c) {
                    s_prefix = pf | ((unsigned int)vq << (p * 8));
                    s_k = k;
                    break;
                }
                k -= c;
            }
        }
        __syncthreads();
    }
    const unsigned int kth = s_prefix;   // key of exact kth-largest value

    // compact kept entries (sim >= kth  <=>  key >= kth, map is monotone)
    for (int i = tid; i < M_DIM; i += NT) {
        unsigned int ky = keys[i];
        if (ky >= kth) {
            int pos = atomicAdd(&s_cnt, 1);
            if (pos < KCAP) { s_idx[pos] = i; s_w[pos] = key2f(ky); }
        }
    }
    __syncthreads();
    const int cnt = min(s_cnt, KCAP);

    // sum of w^2 (one wave)
    if (tid < 64) {
        float s = 0.f;
        for (int i = tid; i < cnt; i += 64) s += s_w[i] * s_w[i];
#pragma unroll
        for (int mk = 32; mk; mk >>= 1) s += __shfl_xor(s, mk, 64);
        if (tid == 0) s_sumw2 = s;
    }
    __syncthreads();

    // read accumulation: 128 columns, 2 threads per column over kept rows
    const int col  = tid & 127;
    const int half = tid >> 7;
    float acc = 0.f;
    const float* mb = mem + (size_t)b * M_DIM * V_DIM;
    for (int j = half; j < cnt; j += 2)
        acc += s_w[j] * mb[(size_t)s_idx[j] * V_DIM + col];
    s_acc[tid] = acc;
    __syncthreads();
    if (tid < 128)
        out[b * V_DIM + tid] =
            s_acc[tid] + s_acc[tid + 128] + s_sumw2 * v[b * V_DIM + tid];
}

extern "C" void kernel_launch(void* const* d_in, const int* in_sizes, int n_in,
                              void* d_out, int out_size, void* d_ws, size_t ws_size,
                              hipStream_t stream) {
    const float* mem   = (const float*)d_in[0];
    const float* v     = (const float*)d_in[1];
    const int*   topk  = (const int*)d_in[2];
    float* out         = (float*)d_out;
    float* sim         = (float*)d_ws;    // B*M floats = 2 MB

    dim3 grid1(M_DIM / 32, B_DIM);
    sim_kernel<<<grid1, 256, 0, stream>>>(mem, v, sim);

    topk_read_kernel<<<B_DIM, 256, 0, stream>>>(mem, v, sim, topk, out);
}

// Round 2
// 378.682 us; speedup vs baseline: 1.1431x; 1.1431x over previous
//
#include <hip/hip_runtime.h>
#include <hip/hip_bf16.h>

#define B_DIM 64
#define M_DIM 8192
#define V_DIM 128
#define EPS 1e-8f
#define KCAP 2048

// monotone float->uint key map (order-preserving, invertible)
__device__ __forceinline__ unsigned int f2key(float f) {
    unsigned int u = __float_as_uint(f);
    return (u & 0x80000000u) ? ~u : (u | 0x80000000u);
}
__device__ __forceinline__ float key2f(unsigned int k) {
    return (k & 0x80000000u) ? __uint_as_float(k & 0x7FFFFFFFu)
                             : __uint_as_float(~k);
}

// ---------------- Kernel 1: cosine similarity -> radix keys ----------------
// grid (M/64, B), block 256 (4 waves). 16 lanes per row, 2 float4/lane:
// 4 rows per wave per iter, 4 iters -> 64 rows/block.
// Reduction: 4 shfl-xor levels (width 16) per quantity, per 4 rows.
__global__ void sim_kernel(const float* __restrict__ mem,
                           const float* __restrict__ v,
                           unsigned int* __restrict__ keys_out) {
    const int b    = blockIdx.y;
    const int m0   = blockIdx.x * 64;
    const int tid  = threadIdx.x;
    const int wave = tid >> 6;
    const int lane = tid & 63;
    const int rw   = lane >> 4;   // row within wave (0..3)
    const int sub  = lane & 15;   // 16 lanes per row

    __shared__ float vs[V_DIM];
    __shared__ float s_invbn;

    if (tid < V_DIM) vs[tid] = v[b * V_DIM + tid] + EPS;
    __syncthreads();

    if (tid < 64) {
        float x0 = vs[tid], x1 = vs[tid + 64];
        float s = x0 * x0 + x1 * x1;
#pragma unroll
        for (int mk = 32; mk; mk >>= 1) s += __shfl_xor(s, mk, 64);
        if (tid == 0) s_invbn = 1.0f / sqrtf(s);   // denom >> EPS always here
    }
    __syncthreads();

    // per-lane v fragment in registers (cols sub*4.. and sub*4+64..)
    const float4 va = *reinterpret_cast<const float4*>(&vs[sub * 4]);
    const float4 vb = *reinterpret_cast<const float4*>(&vs[sub * 4 + 64]);
    const float invbn = s_invbn;

#pragma unroll
    for (int t = 0; t < 4; ++t) {
        const int m = m0 + t * 16 + wave * 4 + rw;
        const float4* rp =
            reinterpret_cast<const float4*>(mem + ((size_t)b * M_DIM + m) * V_DIM);
        float4 x0 = rp[sub];
        float4 x1 = rp[sub + 16];
        float a0 = x0.x + EPS, a1 = x0.y + EPS, a2 = x0.z + EPS, a3 = x0.w + EPS;
        float a4 = x1.x + EPS, a5 = x1.y + EPS, a6 = x1.z + EPS, a7 = x1.w + EPS;
        float dot = a0 * va.x + a1 * va.y + a2 * va.z + a3 * va.w
                  + a4 * vb.x + a5 * vb.y + a6 * vb.z + a7 * vb.w;
        float ss  = a0 * a0 + a1 * a1 + a2 * a2 + a3 * a3
                  + a4 * a4 + a5 * a5 + a6 * a6 + a7 * a7;
#pragma unroll
        for (int mk = 8; mk; mk >>= 1) {
            dot += __shfl_xor(dot, mk, 16);
            ss  += __shfl_xor(ss,  mk, 16);
        }
        if (sub == 0) {
            float sim = dot * rsqrtf(ss) * invbn;
            keys_out[(size_t)b * M_DIM + m] = f2key(sim);
        }
    }
}

// ---------------- Kernel 2: exact top-k select + fused write/read ----------
// One block per batch (256 thr). Byte radix-select with per-wave private
// histograms and a parallel suffix-sum bucket scan (no serial tid0 loop).
__global__ void topk_read_kernel(const float* __restrict__ mem,
                                 const float* __restrict__ v,
                                 const unsigned int* __restrict__ keys_in,
                                 const int* __restrict__ topk_p,
                                 float* __restrict__ out) {
    const int b   = blockIdx.x;
    const int tid = threadIdx.x;
    const int NT  = 256;
    const int wv  = tid >> 6;

    __shared__ unsigned int keys[M_DIM];      // 32 KB
    __shared__ unsigned int hist[4 * 256];    // 4 KB, per-wave private
    __shared__ int          sfx[256];         // suffix sums
    __shared__ unsigned int s_prefix;
    __shared__ int s_k;
    __shared__ int s_cnt;
    __shared__ int   s_idx[KCAP];             // 8 KB
    __shared__ float s_w[KCAP];               // 8 KB
    __shared__ float s_sumw2;
    __shared__ float s_acc[256];

    for (int i = tid; i < M_DIM; i += NT)
        keys[i] = keys_in[(size_t)b * M_DIM + i];
    if (tid == 0) { s_prefix = 0u; s_k = topk_p[0]; s_cnt = 0; }
    __syncthreads();

    for (int p = 3; p >= 0; --p) {
#pragma unroll
        for (int h = tid; h < 1024; h += NT) hist[h] = 0u;
        __syncthreads();
        const unsigned int dm = (p == 3) ? 0u : (0xFFFFFFFFu << ((p + 1) * 8));
        const unsigned int pf = s_prefix;
        const int k_cur = s_k;
        for (int i = tid; i < M_DIM; i += NT) {
            unsigned int ky = keys[i];
            if ((ky & dm) == pf)
                atomicAdd(&hist[wv * 256 + ((ky >> (p * 8)) & 0xFFu)], 1u);
        }
        __syncthreads();
        // combine 4 private hists; suffix-sum (count of buckets >= t)
        int c = (int)(hist[tid] + hist[256 + tid] + hist[512 + tid] + hist[768 + tid]);
        sfx[tid] = c;
        __syncthreads();
#pragma unroll
        for (int off = 1; off < 256; off <<= 1) {
            int x = (tid + off < 256) ? sfx[tid + off] : 0;
            __syncthreads();
            sfx[tid] += x;
            __syncthreads();
        }
        int S_t  = sfx[tid];
        int S_t1 = (tid < 255) ? sfx[tid + 1] : 0;
        if (S_t >= k_cur && S_t1 < k_cur) {
            s_prefix = pf | ((unsigned int)tid << (p * 8));
            s_k = k_cur - S_t1;   // remaining rank within this bucket
        }
        __syncthreads();
    }
    const unsigned int kth = s_prefix;   // exact key of kth-largest

    // compact kept entries: sim >= kth  <=>  key >= kth (monotone map)
    for (int i = tid; i < M_DIM; i += NT) {
        unsigned int ky = keys[i];
        if (ky >= kth) {
            int pos = atomicAdd(&s_cnt, 1);
            if (pos < KCAP) { s_idx[pos] = i; s_w[pos] = key2f(ky); }
        }
    }
    __syncthreads();
    const int cnt = min(s_cnt, KCAP);

    if (tid < 64) {
        float s = 0.f;
        for (int i = tid; i < cnt; i += 64) s += s_w[i] * s_w[i];
#pragma unroll
        for (int mk = 32; mk; mk >>= 1) s += __shfl_xor(s, mk, 64);
        if (tid == 0) s_sumw2 = s;
    }
    __syncthreads();

    // read accumulation: 128 cols, 2 threads/col, 4-way unrolled over rows
    const int col  = tid & 127;
    const int half = tid >> 7;
    const float* mb = mem + (size_t)b * M_DIM * V_DIM;
    float a0 = 0.f, a1 = 0.f, a2 = 0.f, a3 = 0.f;
    int j = half;
    for (; j + 6 < cnt; j += 8) {
        a0 += s_w[j]     * mb[(size_t)s_idx[j]     * V_DIM + col];
        a1 += s_w[j + 2] * mb[(size_t)s_idx[j + 2] * V_DIM + col];
        a2 += s_w[j + 4] * mb[(size_t)s_idx[j + 4] * V_DIM + col];
        a3 += s_w[j + 6] * mb[(size_t)s_idx[j + 6] * V_DIM + col];
    }
    for (; j < cnt; j += 2)
        a0 += s_w[j] * mb[(size_t)s_idx[j] * V_DIM + col];
    s_acc[tid] = (a0 + a1) + (a2 + a3);
    __syncthreads();
    if (tid < 128)
        out[b * V_DIM + tid] =
            s_acc[tid] + s_acc[tid + 128] + s_sumw2 * v[b * V_DIM + tid];
}

extern "C" void kernel_launch(void* const* d_in, const int* in_sizes, int n_in,
                              void* d_out, int out_size, void* d_ws, size_t ws_size,
                              hipStream_t stream) {
    const float* mem  = (const float*)d_in[0];
    const float* v    = (const float*)d_in[1];
    const int*   topk = (const int*)d_in[2];
    float* out        = (float*)d_out;
    unsigned int* keys = (unsigned int*)d_ws;   // B*M uints = 2 MB

    dim3 grid1(M_DIM / 64, B_DIM);
    sim_kernel<<<grid1, 256, 0, stream>>>(mem, v, keys);

    topk_read_kernel<<<B_DIM, 256, 0, stream>>>(mem, v, keys, topk, out);
}